// Round 8
// baseline (7060.787 us; speedup 1.0000x reference)
//
#include <hip/hip_runtime.h>
#include <math.h>

// B=32, D=256, T=1024, H=512, 4H=2048
// THIS ROUND: participant-count reduction. 2 groups x 8 blocks x 1024 threads
// (16 waves); block owns 64 h-cols. Wave = (gate, khalf, tilehalf): 2 col-tiles
// x 8 K-granules = 16 MFMAs/wave/step — per-thread resources identical to the
// proven 512-thread kernel (whh_frag[2][8], wih_frag[2][4], 128 VGPR).
// Exchange protocol = bit-identical r2 skeleton: publish dword atomics ->
// per-wave vmcnt drain -> barrier -> tid0 flag; wave0 polls 8 flag lines;
// barrier; 16B/thread bulk load (exactly one granule) -> swizzled h_lds.
// Rationale: all protocol variants land ~3000us; the untried axis is N
// participants (skew E[max], flag count, barrier population). N: 16 -> 8.
// LDS: h_lds 16KB (XOR-granule swizzle), gates 33.3KB, out_stage 69.6KB = 119KB.
// ws: [0,16MB) xT bf16 [T][B][D]; +16MB flags (8KB); then hbuf dw [2grp][2ph][16][256]

using short8  = __attribute__((ext_vector_type(8))) short;
using f32x4   = __attribute__((ext_vector_type(4))) float;
using float4v = __attribute__((ext_vector_type(4))) float;
using uint4v  = __attribute__((ext_vector_type(4))) unsigned;

__device__ inline unsigned short f2bf(float f) {
    unsigned u = __float_as_uint(f);
    unsigned r = u + 0x7fffu + ((u >> 16) & 1u);
    return (unsigned short)(r >> 16);
}
__device__ inline float fsig(float x) {
    return __builtin_amdgcn_rcpf(1.0f + __expf(-x));
}
__device__ inline float ftanh(float x) {
    return 2.0f * __builtin_amdgcn_rcpf(1.0f + __expf(-2.0f * x)) - 1.0f;
}

__global__ void zero_flags(unsigned* p) {
    p[blockIdx.x * 256 + threadIdx.x] = 0u;
}

// ---------------- Phase 1: xT[t][b][d] = bf16(x[b][d][t]) ----------------
__global__ __launch_bounds__(256) void x_transpose(const float* __restrict__ x,
                                                   unsigned short* __restrict__ xT) {
    __shared__ unsigned short tile[64][65];
    const int tid = threadIdx.x;
    const int t0 = blockIdx.x * 64, d0 = blockIdx.y * 64, b = blockIdx.z;
    for (int p = 0; p < 16; p++) {
        int d = p * 4 + (tid >> 6);
        int t = tid & 63;
        tile[d][t] = f2bf(x[(b * 256 + d0 + d) * 1024 + t0 + t]);
    }
    __syncthreads();
    for (int p = 0; p < 16; p++) {
        int t = p * 4 + (tid >> 6);
        int d = tid & 63;
        xT[(size_t)(t0 + t) * 8192 + b * 256 + d0 + d] = tile[d][t];
    }
}

// ---------------- Phase 2: recurrence ----------------
#define GS 65    // gates_lds row stride (floats), 128 rows x 64 cols
#define OS 17    // out_stage row stride (floats)

__global__ __launch_bounds__(1024) void lstm_rec(const unsigned short* __restrict__ xT,
                                                 const float* __restrict__ Wih,
                                                 const float* __restrict__ Whh,
                                                 const float* __restrict__ bih,
                                                 const float* __restrict__ bhh,
                                                 float* __restrict__ out,
                                                 unsigned* flags,
                                                 unsigned* hbuf) {
    __shared__ __align__(16) unsigned short h_lds[16 * 512];      // 16 KB, swizzled
    __shared__ float gates_lds[128 * GS];                         // 33.3 KB (2 partials)
    __shared__ float out_stage[1024 * OS];                        // 69.6 KB

    const int tid  = threadIdx.x;
    const int wave = tid >> 6;
    const int lane = tid & 63;
    const int quad = lane >> 4, l15 = lane & 15;
    const int l7   = l15 & 7;
    const int group = blockIdx.x & 1;
    const int g     = blockIdx.x >> 1;         // h-slice [64g, 64g+64), g in [0,8)
    const int gate  = wave >> 2;               // i,f,g,o
    const int kh    = (wave >> 1) & 1;         // K-half
    const int th    = wave & 1;                // tile-half: tiles {2th, 2th+1}

    // one-time weight preload: 2 col-tiles x (8 h-ks + 4 x-ks), K-range = kh half
    short8 whh_frag[2][8];
    short8 wih_frag[2][4];
    float bias_t[2];
    for (int tile = 0; tile < 2; tile++) {
        const int nrow = gate * 512 + g * 64 + th * 32 + tile * 16 + l15;
        for (int ks = 0; ks < 8; ks++) {
            const float* p = &Whh[(size_t)nrow * 512 + kh * 256 + ks * 32 + quad * 8];
            short8 v;
            for (int j = 0; j < 8; j++) v[j] = (short)f2bf(p[j]);
            whh_frag[tile][ks] = v;
        }
        for (int ks = 0; ks < 4; ks++) {
            const float* p = &Wih[(size_t)nrow * 256 + kh * 128 + ks * 32 + quad * 8];
            short8 v;
            for (int j = 0; j < 8; j++) v[j] = (short)f2bf(p[j]);
            wih_frag[tile][ks] = v;
        }
        bias_t[tile] = (kh == 0) ? (bih[nrow] + bhh[nrow]) : 0.0f;
    }

    const int eb = tid >> 6, ek = tid & 63;    // elementwise: local batch, local col
    const int e7 = eb & 7;
    const int hidx = g * 64 + ek;
    const bool remote = ((ek >> 3) != g);      // consumer granule ek: own granules [8g,8g+8)

    for (int i = tid; i < 16 * 512; i += 1024) h_lds[i] = 0;

    // x A-fragment source for this lane: row = batch l15, K-chunk = kh/ks/quad
    const unsigned short* xbase = xT + (size_t)(group * 16 + l15) * 256 + kh * 128 + quad * 8;

    // prefetch x for t=0 into registers
    short8 xf[4];
#pragma unroll
    for (int ks = 0; ks < 4; ks++)
        xf[ks] = *(const short8*)(xbase + (size_t)0 * 8192 + ks * 32);

    float c = 0.0f;
    float* out_base = out + ((size_t)(group * 16 + eb) * 512 + hidx) * 1024;
    unsigned* my_flags = flags + group * 512;            // 8 flags, 128 B apart
    unsigned* hb_base  = hbuf + group * 8192;            // [2 phase][16 b][256 cp]

    __syncthreads();

    // t=0 x-part
    f32x4 acc0 = f32x4{bias_t[0], bias_t[0], bias_t[0], bias_t[0]};
    f32x4 acc1 = f32x4{bias_t[1], bias_t[1], bias_t[1], bias_t[1]};
#pragma unroll
    for (int ks = 0; ks < 4; ks++) {
        acc0 = __builtin_amdgcn_mfma_f32_16x16x32_bf16(xf[ks], wih_frag[0][ks], acc0, 0, 0, 0);
        acc1 = __builtin_amdgcn_mfma_f32_16x16x32_bf16(xf[ks], wih_frag[1][ks], acc1, 0, 0, 0);
    }

    for (int t = 0; t < 1024; t++) {
        // P0: issue x prefetch for t+1 into registers (latency hidden under step)
        if (t + 1 < 1024) {
#pragma unroll
            for (int ks = 0; ks < 4; ks++)
                xf[ks] = *(const short8*)(xbase + (size_t)(t + 1) * 8192 + ks * 32);
        }

        // P1: h-part: 8 A-reads feed 16 MFMAs (2 col-tiles)
#pragma unroll
        for (int ks = 0; ks < 8; ks++) {
            short8 af = *(const short8*)&h_lds[l15 * 512 + (((kh << 5) + (ks << 2) + quad) ^ l7) * 8];
            acc0 = __builtin_amdgcn_mfma_f32_16x16x32_bf16(af, whh_frag[0][ks], acc0, 0, 0, 0);
            acc1 = __builtin_amdgcn_mfma_f32_16x16x32_bf16(af, whh_frag[1][ks], acc1, 0, 0, 0);
        }
        // P2: write K-half partials; row = (kh*4+gate)*16 + batch, col = 64-wide
        {
            const int prow = (kh * 4 + gate) * 16;
            const int pcol = th * 32;
#pragma unroll
            for (int r = 0; r < 4; r++) {
                gates_lds[(prow + quad * 4 + r) * GS + pcol + l15]      = acc0[r];
                gates_lds[(prow + quad * 4 + r) * GS + pcol + 16 + l15] = acc1[r];
            }
        }
        // B1: raw barrier, LDS drain only (x loads stay in flight)
        asm volatile("s_waitcnt lgkmcnt(0)" ::: "memory");
        __builtin_amdgcn_sched_barrier(0);
        __builtin_amdgcn_s_barrier();
        __builtin_amdgcn_sched_barrier(0);

        // P4: elementwise: sum K-half partials, gate math
        float iv = gates_lds[(0 * 16 + eb) * GS + ek] + gates_lds[(4 * 16 + eb) * GS + ek];
        float fv = gates_lds[(1 * 16 + eb) * GS + ek] + gates_lds[(5 * 16 + eb) * GS + ek];
        float gv = gates_lds[(2 * 16 + eb) * GS + ek] + gates_lds[(6 * 16 + eb) * GS + ek];
        float ov = gates_lds[(3 * 16 + eb) * GS + ek] + gates_lds[(7 * 16 + eb) * GS + ek];
        iv = fsig(iv); fv = fsig(fv); gv = ftanh(gv); ov = fsig(ov);
        c = fv * c + iv * gv;
        float h = ov * ftanh(c);

        out_stage[tid * OS + (t & 15)] = h;

        // own column straight into h_lds (post-B1, disjoint from other writers)
        unsigned my = f2bf(h);
        {
            int phys = (g * 8 + (ek >> 3)) ^ e7;
            h_lds[eb * 512 + phys * 8 + (ek & 7)] = (unsigned short)my;
        }

        // publish packed bf16x2 dwords (fire now, drain later)
        unsigned nb = (unsigned)__shfl_xor((int)my, 1);
        if (t < 1023 && !(ek & 1)) {
            __hip_atomic_store(&hb_base[(t & 1) * 4096 + eb * 256 + g * 32 + (ek >> 1)],
                               my | (nb << 16), __ATOMIC_RELAXED, __HIP_MEMORY_SCOPE_AGENT);
        }

        if (t == 1023) break;

        // ---- next step's x-part while publish stores drain ----
        acc0 = f32x4{bias_t[0], bias_t[0], bias_t[0], bias_t[0]};
        acc1 = f32x4{bias_t[1], bias_t[1], bias_t[1], bias_t[1]};
#pragma unroll
        for (int ks = 0; ks < 4; ks++) {
            acc0 = __builtin_amdgcn_mfma_f32_16x16x32_bf16(xf[ks], wih_frag[0][ks], acc0, 0, 0, 0);
            acc1 = __builtin_amdgcn_mfma_f32_16x16x32_bf16(xf[ks], wih_frag[1][ks], acc1, 0, 0, 0);
        }

        // ---- drain own publish stores, then flag (per-wave drain + barrier
        // guarantees whole block's stores are committed before tid0 flags) ----
        asm volatile("s_waitcnt vmcnt(0)" ::: "memory");
        __builtin_amdgcn_sched_barrier(0);
        __builtin_amdgcn_s_barrier();
        __builtin_amdgcn_sched_barrier(0);
        if (tid == 0)
            __hip_atomic_store(&my_flags[g * 32], (unsigned)(t + 1),
                               __ATOMIC_RELAXED, __HIP_MEMORY_SCOPE_AGENT);

        // out flush every 16 steps (own LDS row) — after flag: rides the poll
        // shadow; HBM stores retire long before the next 16th-step drain.
        if ((t & 15) == 15) {
            int t0 = t & ~15;
#pragma unroll
            for (int q = 0; q < 4; q++) {
                float4v v = *(const float4v*)&out_stage[tid * OS + q * 4];
                *(float4v*)&out_base[t0 + q * 4] = v;
            }
        }

        // ---- wait for all 8 producers (tiny poll surface: 8 lanes x 4B) ----
        if (wave == 0 && lane < 8) {
            while (__hip_atomic_load(&my_flags[lane * 32], __ATOMIC_RELAXED,
                                     __HIP_MEMORY_SCOPE_AGENT) <= (unsigned)t) { }
        }
        __builtin_amdgcn_s_barrier();
        __builtin_amdgcn_sched_barrier(0);

        // ---- bulk-load remote h_t (16 B/thread = one granule), swizzled scatter ----
        if (remote) {
            const unsigned long long* src =
                (const unsigned long long*)&hb_base[(t & 1) * 4096 + eb * 256 + ek * 4];
            unsigned long long v0 = __hip_atomic_load(src + 0, __ATOMIC_RELAXED, __HIP_MEMORY_SCOPE_AGENT);
            unsigned long long v1 = __hip_atomic_load(src + 1, __ATOMIC_RELAXED, __HIP_MEMORY_SCOPE_AGENT);
            int phys = ek ^ e7;
            *(uint4v*)&h_lds[eb * 512 + phys * 8] =
                uint4v{(unsigned)v0, (unsigned)(v0 >> 32), (unsigned)v1, (unsigned)(v1 >> 32)};
        }
        // B4: raw barrier, LDS drain only (h_lds writes incl. own-col)
        asm volatile("s_waitcnt lgkmcnt(0)" ::: "memory");
        __builtin_amdgcn_sched_barrier(0);
        __builtin_amdgcn_s_barrier();
        __builtin_amdgcn_sched_barrier(0);
    }

    // epilogue: flush last 16 outputs (t = 1008..1023)
#pragma unroll
    for (int q = 0; q < 4; q++) {
        float4v v = *(const float4v*)&out_stage[tid * OS + q * 4];
        *(float4v*)&out_base[1008 + q * 4] = v;
    }
}

extern "C" void kernel_launch(void* const* d_in, const int* in_sizes, int n_in,
                              void* d_out, int out_size, void* d_ws, size_t ws_size,
                              hipStream_t stream) {
    (void)in_sizes; (void)n_in; (void)out_size; (void)ws_size;
    const float* x   = (const float*)d_in[0];
    const float* Wih = (const float*)d_in[1];
    const float* Whh = (const float*)d_in[2];
    const float* bih = (const float*)d_in[3];
    const float* bhh = (const float*)d_in[4];
    float* out = (float*)d_out;

    char* ws = (char*)d_ws;
    unsigned short* xT = (unsigned short*)ws;                 // 16,777,216 B
    unsigned* flags    = (unsigned*)(ws + 16777216);          // 8 KB
    unsigned* hbuf     = (unsigned*)(ws + 16777216 + 8192);   // 64 KB

    zero_flags<<<8, 256, 0, stream>>>(flags);
    dim3 gT(16, 4, 32);
    x_transpose<<<gT, 256, 0, stream>>>(x, xT);
    lstm_rec<<<16, 1024, 0, stream>>>(xT, Wih, Whh, bih, bhh, out, flags, hbuf);
}

// Round 9
// 7058.723 us; speedup vs baseline: 1.0003x; 1.0003x over previous
//
#include <hip/hip_runtime.h>
#include <math.h>

// B=32, D=256, T=1024, H=512, 4H=2048
// ROUND 9 = ROUND 8 + __launch_bounds__(1024, 4). r8's probe was confounded:
// default launch bounds targeted 8 waves/EU -> 64-VGPR cap -> persistent weight
// fragments spilled to scratch (WRITE_SIZE +37MB, VALUBusy halved). (1024,4)
// = 4 waves/EU = 1 block/CU = 128-VGPR budget, the proven per-thread footprint.
// Geometry: 2 groups x 8 blocks x 1024 threads (16 waves); block owns 64 h-cols.
// Wave = (gate, khalf, tilehalf): 2 col-tiles x 8 K-granules = 16 MFMAs/wave/step.
// Exchange protocol = r2 skeleton: publish dword atomics -> per-wave vmcnt drain
// -> barrier -> tid0 flag; wave0 polls 8 flag lines; barrier; 16B/thread bulk
// load (one granule) -> swizzled h_lds scatter.
// Hypothesis under test: participant count N=16->8 cuts flag skew E[max] +
// poll surface; protocol variants don't help (r1/r5/r6/r7), N might.
// LDS: h_lds 16KB (XOR-granule swizzle), gates 33.3KB, out_stage 69.6KB = 119KB.
// ws: [0,16MB) xT bf16 [T][B][D]; +16MB flags (8KB); then hbuf dw [2grp][2ph][16][256]

using short8  = __attribute__((ext_vector_type(8))) short;
using f32x4   = __attribute__((ext_vector_type(4))) float;
using float4v = __attribute__((ext_vector_type(4))) float;
using uint4v  = __attribute__((ext_vector_type(4))) unsigned;

__device__ inline unsigned short f2bf(float f) {
    unsigned u = __float_as_uint(f);
    unsigned r = u + 0x7fffu + ((u >> 16) & 1u);
    return (unsigned short)(r >> 16);
}
__device__ inline float fsig(float x) {
    return __builtin_amdgcn_rcpf(1.0f + __expf(-x));
}
__device__ inline float ftanh(float x) {
    return 2.0f * __builtin_amdgcn_rcpf(1.0f + __expf(-2.0f * x)) - 1.0f;
}

__global__ void zero_flags(unsigned* p) {
    p[blockIdx.x * 256 + threadIdx.x] = 0u;
}

// ---------------- Phase 1: xT[t][b][d] = bf16(x[b][d][t]) ----------------
__global__ __launch_bounds__(256) void x_transpose(const float* __restrict__ x,
                                                   unsigned short* __restrict__ xT) {
    __shared__ unsigned short tile[64][65];
    const int tid = threadIdx.x;
    const int t0 = blockIdx.x * 64, d0 = blockIdx.y * 64, b = blockIdx.z;
    for (int p = 0; p < 16; p++) {
        int d = p * 4 + (tid >> 6);
        int t = tid & 63;
        tile[d][t] = f2bf(x[(b * 256 + d0 + d) * 1024 + t0 + t]);
    }
    __syncthreads();
    for (int p = 0; p < 16; p++) {
        int t = p * 4 + (tid >> 6);
        int d = tid & 63;
        xT[(size_t)(t0 + t) * 8192 + b * 256 + d0 + d] = tile[d][t];
    }
}

// ---------------- Phase 2: recurrence ----------------
#define GS 65    // gates_lds row stride (floats), 128 rows x 64 cols
#define OS 17    // out_stage row stride (floats)

__global__ __launch_bounds__(1024, 4) void lstm_rec(const unsigned short* __restrict__ xT,
                                                    const float* __restrict__ Wih,
                                                    const float* __restrict__ Whh,
                                                    const float* __restrict__ bih,
                                                    const float* __restrict__ bhh,
                                                    float* __restrict__ out,
                                                    unsigned* flags,
                                                    unsigned* hbuf) {
    __shared__ __align__(16) unsigned short h_lds[16 * 512];      // 16 KB, swizzled
    __shared__ float gates_lds[128 * GS];                         // 33.3 KB (2 partials)
    __shared__ float out_stage[1024 * OS];                        // 69.6 KB

    const int tid  = threadIdx.x;
    const int wave = tid >> 6;
    const int lane = tid & 63;
    const int quad = lane >> 4, l15 = lane & 15;
    const int l7   = l15 & 7;
    const int group = blockIdx.x & 1;
    const int g     = blockIdx.x >> 1;         // h-slice [64g, 64g+64), g in [0,8)
    const int gate  = wave >> 2;               // i,f,g,o
    const int kh    = (wave >> 1) & 1;         // K-half
    const int th    = wave & 1;                // tile-half: tiles {2th, 2th+1}

    // one-time weight preload: 2 col-tiles x (8 h-ks + 4 x-ks), K-range = kh half
    short8 whh_frag[2][8];
    short8 wih_frag[2][4];
    float bias_t[2];
    for (int tile = 0; tile < 2; tile++) {
        const int nrow = gate * 512 + g * 64 + th * 32 + tile * 16 + l15;
        for (int ks = 0; ks < 8; ks++) {
            const float* p = &Whh[(size_t)nrow * 512 + kh * 256 + ks * 32 + quad * 8];
            short8 v;
            for (int j = 0; j < 8; j++) v[j] = (short)f2bf(p[j]);
            whh_frag[tile][ks] = v;
        }
        for (int ks = 0; ks < 4; ks++) {
            const float* p = &Wih[(size_t)nrow * 256 + kh * 128 + ks * 32 + quad * 8];
            short8 v;
            for (int j = 0; j < 8; j++) v[j] = (short)f2bf(p[j]);
            wih_frag[tile][ks] = v;
        }
        bias_t[tile] = (kh == 0) ? (bih[nrow] + bhh[nrow]) : 0.0f;
    }

    const int eb = tid >> 6, ek = tid & 63;    // elementwise: local batch, local col
    const int e7 = eb & 7;
    const int hidx = g * 64 + ek;
    const bool remote = ((ek >> 3) != g);      // consumer granule ek: own granules [8g,8g+8)

    for (int i = tid; i < 16 * 512; i += 1024) h_lds[i] = 0;

    // x A-fragment source for this lane: row = batch l15, K-chunk = kh/ks/quad
    const unsigned short* xbase = xT + (size_t)(group * 16 + l15) * 256 + kh * 128 + quad * 8;

    // prefetch x for t=0 into registers
    short8 xf[4];
#pragma unroll
    for (int ks = 0; ks < 4; ks++)
        xf[ks] = *(const short8*)(xbase + (size_t)0 * 8192 + ks * 32);

    float c = 0.0f;
    float* out_base = out + ((size_t)(group * 16 + eb) * 512 + hidx) * 1024;
    unsigned* my_flags = flags + group * 512;            // 8 flags, 128 B apart
    unsigned* hb_base  = hbuf + group * 8192;            // [2 phase][16 b][256 cp]

    __syncthreads();

    // t=0 x-part
    f32x4 acc0 = f32x4{bias_t[0], bias_t[0], bias_t[0], bias_t[0]};
    f32x4 acc1 = f32x4{bias_t[1], bias_t[1], bias_t[1], bias_t[1]};
#pragma unroll
    for (int ks = 0; ks < 4; ks++) {
        acc0 = __builtin_amdgcn_mfma_f32_16x16x32_bf16(xf[ks], wih_frag[0][ks], acc0, 0, 0, 0);
        acc1 = __builtin_amdgcn_mfma_f32_16x16x32_bf16(xf[ks], wih_frag[1][ks], acc1, 0, 0, 0);
    }

    for (int t = 0; t < 1024; t++) {
        // P0: issue x prefetch for t+1 into registers (latency hidden under step)
        if (t + 1 < 1024) {
#pragma unroll
            for (int ks = 0; ks < 4; ks++)
                xf[ks] = *(const short8*)(xbase + (size_t)(t + 1) * 8192 + ks * 32);
        }

        // P1: h-part: 8 A-reads feed 16 MFMAs (2 col-tiles)
#pragma unroll
        for (int ks = 0; ks < 8; ks++) {
            short8 af = *(const short8*)&h_lds[l15 * 512 + (((kh << 5) + (ks << 2) + quad) ^ l7) * 8];
            acc0 = __builtin_amdgcn_mfma_f32_16x16x32_bf16(af, whh_frag[0][ks], acc0, 0, 0, 0);
            acc1 = __builtin_amdgcn_mfma_f32_16x16x32_bf16(af, whh_frag[1][ks], acc1, 0, 0, 0);
        }
        // P2: write K-half partials; row = (kh*4+gate)*16 + batch, col = 64-wide
        {
            const int prow = (kh * 4 + gate) * 16;
            const int pcol = th * 32;
#pragma unroll
            for (int r = 0; r < 4; r++) {
                gates_lds[(prow + quad * 4 + r) * GS + pcol + l15]      = acc0[r];
                gates_lds[(prow + quad * 4 + r) * GS + pcol + 16 + l15] = acc1[r];
            }
        }
        // B1: raw barrier, LDS drain only (x loads stay in flight)
        asm volatile("s_waitcnt lgkmcnt(0)" ::: "memory");
        __builtin_amdgcn_sched_barrier(0);
        __builtin_amdgcn_s_barrier();
        __builtin_amdgcn_sched_barrier(0);

        // P4: elementwise: sum K-half partials, gate math
        float iv = gates_lds[(0 * 16 + eb) * GS + ek] + gates_lds[(4 * 16 + eb) * GS + ek];
        float fv = gates_lds[(1 * 16 + eb) * GS + ek] + gates_lds[(5 * 16 + eb) * GS + ek];
        float gv = gates_lds[(2 * 16 + eb) * GS + ek] + gates_lds[(6 * 16 + eb) * GS + ek];
        float ov = gates_lds[(3 * 16 + eb) * GS + ek] + gates_lds[(7 * 16 + eb) * GS + ek];
        iv = fsig(iv); fv = fsig(fv); gv = ftanh(gv); ov = fsig(ov);
        c = fv * c + iv * gv;
        float h = ov * ftanh(c);

        out_stage[tid * OS + (t & 15)] = h;

        // own column straight into h_lds (post-B1, disjoint from other writers)
        unsigned my = f2bf(h);
        {
            int phys = (g * 8 + (ek >> 3)) ^ e7;
            h_lds[eb * 512 + phys * 8 + (ek & 7)] = (unsigned short)my;
        }

        // publish packed bf16x2 dwords (fire now, drain later)
        unsigned nb = (unsigned)__shfl_xor((int)my, 1);
        if (t < 1023 && !(ek & 1)) {
            __hip_atomic_store(&hb_base[(t & 1) * 4096 + eb * 256 + g * 32 + (ek >> 1)],
                               my | (nb << 16), __ATOMIC_RELAXED, __HIP_MEMORY_SCOPE_AGENT);
        }

        if (t == 1023) break;

        // ---- next step's x-part while publish stores drain ----
        acc0 = f32x4{bias_t[0], bias_t[0], bias_t[0], bias_t[0]};
        acc1 = f32x4{bias_t[1], bias_t[1], bias_t[1], bias_t[1]};
#pragma unroll
        for (int ks = 0; ks < 4; ks++) {
            acc0 = __builtin_amdgcn_mfma_f32_16x16x32_bf16(xf[ks], wih_frag[0][ks], acc0, 0, 0, 0);
            acc1 = __builtin_amdgcn_mfma_f32_16x16x32_bf16(xf[ks], wih_frag[1][ks], acc1, 0, 0, 0);
        }

        // ---- drain own publish stores, then flag (per-wave drain + barrier
        // guarantees whole block's stores are committed before tid0 flags) ----
        asm volatile("s_waitcnt vmcnt(0)" ::: "memory");
        __builtin_amdgcn_sched_barrier(0);
        __builtin_amdgcn_s_barrier();
        __builtin_amdgcn_sched_barrier(0);
        if (tid == 0)
            __hip_atomic_store(&my_flags[g * 32], (unsigned)(t + 1),
                               __ATOMIC_RELAXED, __HIP_MEMORY_SCOPE_AGENT);

        // out flush every 16 steps (own LDS row) — after flag: rides the poll
        // shadow; HBM stores retire long before the next 16th-step drain.
        if ((t & 15) == 15) {
            int t0 = t & ~15;
#pragma unroll
            for (int q = 0; q < 4; q++) {
                float4v v = *(const float4v*)&out_stage[tid * OS + q * 4];
                *(float4v*)&out_base[t0 + q * 4] = v;
            }
        }

        // ---- wait for all 8 producers (tiny poll surface: 8 lanes x 4B) ----
        if (wave == 0 && lane < 8) {
            while (__hip_atomic_load(&my_flags[lane * 32], __ATOMIC_RELAXED,
                                     __HIP_MEMORY_SCOPE_AGENT) <= (unsigned)t) { }
        }
        __builtin_amdgcn_s_barrier();
        __builtin_amdgcn_sched_barrier(0);

        // ---- bulk-load remote h_t (16 B/thread = one granule), swizzled scatter ----
        if (remote) {
            const unsigned long long* src =
                (const unsigned long long*)&hb_base[(t & 1) * 4096 + eb * 256 + ek * 4];
            unsigned long long v0 = __hip_atomic_load(src + 0, __ATOMIC_RELAXED, __HIP_MEMORY_SCOPE_AGENT);
            unsigned long long v1 = __hip_atomic_load(src + 1, __ATOMIC_RELAXED, __HIP_MEMORY_SCOPE_AGENT);
            int phys = ek ^ e7;
            *(uint4v*)&h_lds[eb * 512 + phys * 8] =
                uint4v{(unsigned)v0, (unsigned)(v0 >> 32), (unsigned)v1, (unsigned)(v1 >> 32)};
        }
        // B4: raw barrier, LDS drain only (h_lds writes incl. own-col)
        asm volatile("s_waitcnt lgkmcnt(0)" ::: "memory");
        __builtin_amdgcn_sched_barrier(0);
        __builtin_amdgcn_s_barrier();
        __builtin_amdgcn_sched_barrier(0);
    }

    // epilogue: flush last 16 outputs (t = 1008..1023)
#pragma unroll
    for (int q = 0; q < 4; q++) {
        float4v v = *(const float4v*)&out_stage[tid * OS + q * 4];
        *(float4v*)&out_base[1008 + q * 4] = v;
    }
}

extern "C" void kernel_launch(void* const* d_in, const int* in_sizes, int n_in,
                              void* d_out, int out_size, void* d_ws, size_t ws_size,
                              hipStream_t stream) {
    (void)in_sizes; (void)n_in; (void)out_size; (void)ws_size;
    const float* x   = (const float*)d_in[0];
    const float* Wih = (const float*)d_in[1];
    const float* Whh = (const float*)d_in[2];
    const float* bih = (const float*)d_in[3];
    const float* bhh = (const float*)d_in[4];
    float* out = (float*)d_out;

    char* ws = (char*)d_ws;
    unsigned short* xT = (unsigned short*)ws;                 // 16,777,216 B
    unsigned* flags    = (unsigned*)(ws + 16777216);          // 8 KB
    unsigned* hbuf     = (unsigned*)(ws + 16777216 + 8192);   // 64 KB

    zero_flags<<<8, 256, 0, stream>>>(flags);
    dim3 gT(16, 4, 32);
    x_transpose<<<gT, 256, 0, stream>>>(x, xT);
    lstm_rec<<<16, 1024, 0, stream>>>(xT, Wih, Whh, bih, bhh, out, flags, hbuf);
}

// Round 10
// 3086.780 us; speedup vs baseline: 2.2874x; 2.2868x over previous
//
#include <hip/hip_runtime.h>
#include <math.h>

// B=32, D=256, T=1024, H=512, 4H=2048
// Two independent groups of 16 blocks; group owns 16 batches, block owns 32 h-cols.
// Wave layout: wave = (gate, khalf). Each wave: half of K, both 16-col tiles.
// Exchange: publish dword atomics -> s_waitcnt -> flag; poll flags; bulk load.
// LDS: XOR-granule swizzle (16B granule ^ (row&7)), no padding.
// ws: [0,16MB) xT bf16 [T][B][D]; +16MB flags (8KB); then hbuf dw [2grp][2ph][16][256]
//
// ROUND 10 = round-0 champion (2985us, best of 10 rounds) + ONE isolated fix:
// the every-16-step out-flush moved from BEFORE the pre-flag vmcnt(0) drain to
// AFTER the flag store. Previously every 16th step the whole group's flag chain
// waited on a 32KB HBM store burst; now those stores drain inside the poll/
// bulk-load shadow (retired well before the next step's drain).
// Session ledger (why nothing else): r2 x-in-regs/lgkm-barriers 3061; r6 pipelined
// per-wave consume 3175; r5 single-counter 3468+unstable; r1 tagged-data 3852;
// r7 MFMA-from-hbuf 5832; r8/r9 N=8 geometry 6980 (VGPR-confounded); r3/r4 sc0
// XCD-local medium: failed. The agent-scope exchange legs are the floor.

using short8  = __attribute__((ext_vector_type(8))) short;
using f32x4   = __attribute__((ext_vector_type(4))) float;
using float4v = __attribute__((ext_vector_type(4))) float;
using uint4v  = __attribute__((ext_vector_type(4))) unsigned;

__device__ inline unsigned short f2bf(float f) {
    unsigned u = __float_as_uint(f);
    unsigned r = u + 0x7fffu + ((u >> 16) & 1u);
    return (unsigned short)(r >> 16);
}
__device__ inline float fsig(float x) {
    return __builtin_amdgcn_rcpf(1.0f + __expf(-x));
}
__device__ inline float ftanh(float x) {
    return 2.0f * __builtin_amdgcn_rcpf(1.0f + __expf(-2.0f * x)) - 1.0f;
}

__global__ void zero_flags(unsigned* p) {
    p[blockIdx.x * 256 + threadIdx.x] = 0u;
}

// ---------------- Phase 1: xT[t][b][d] = bf16(x[b][d][t]) ----------------
__global__ __launch_bounds__(256) void x_transpose(const float* __restrict__ x,
                                                   unsigned short* __restrict__ xT) {
    __shared__ unsigned short tile[64][65];
    const int tid = threadIdx.x;
    const int t0 = blockIdx.x * 64, d0 = blockIdx.y * 64, b = blockIdx.z;
    for (int p = 0; p < 16; p++) {
        int d = p * 4 + (tid >> 6);
        int t = tid & 63;
        tile[d][t] = f2bf(x[(b * 256 + d0 + d) * 1024 + t0 + t]);
    }
    __syncthreads();
    for (int p = 0; p < 16; p++) {
        int t = p * 4 + (tid >> 6);
        int d = tid & 63;
        xT[(size_t)(t0 + t) * 8192 + b * 256 + d0 + d] = tile[d][t];
    }
}

// ---------------- Phase 2: recurrence ----------------
#define GS 33    // gates_lds row stride (floats)
#define OS 17    // out_stage row stride (floats)

__global__ __launch_bounds__(512) void lstm_rec(const unsigned short* __restrict__ xT,
                                                const float* __restrict__ Wih,
                                                const float* __restrict__ Whh,
                                                const float* __restrict__ bih,
                                                const float* __restrict__ bhh,
                                                float* __restrict__ out,
                                                unsigned* flags,
                                                unsigned* hbuf) {
    __shared__ __align__(16) unsigned short h_lds[16 * 512];      // 16 KB, swizzled
    __shared__ __align__(16) unsigned short x_lds[2][16 * 256];   // 16 KB, swizzled
    __shared__ float gates_lds[8 * 16 * GS];                      // 16.9 KB (2 partials)
    __shared__ float out_stage[512 * OS];                         // 34.8 KB

    const int tid  = threadIdx.x;
    const int wave = tid >> 6;
    const int lane = tid & 63;
    const int quad = lane >> 4, l15 = lane & 15;
    const int l7   = l15 & 7;
    const int group = blockIdx.x & 1;
    const int g     = blockIdx.x >> 1;         // h-slice [32g, 32g+32)
    const int gate  = wave >> 1;               // i,f,g,o
    const int kh    = wave & 1;                // K-half

    // one-time weight preload: 2 col-tiles x (8 h-ks + 4 x-ks), K-range = kh half
    short8 whh_frag[2][8];
    short8 wih_frag[2][4];
    float bias_t[2];
    for (int tile = 0; tile < 2; tile++) {
        const int nrow = gate * 512 + g * 32 + tile * 16 + l15;
        for (int ks = 0; ks < 8; ks++) {
            const float* p = &Whh[(size_t)nrow * 512 + kh * 256 + ks * 32 + quad * 8];
            short8 v;
            for (int j = 0; j < 8; j++) v[j] = (short)f2bf(p[j]);
            whh_frag[tile][ks] = v;
        }
        for (int ks = 0; ks < 4; ks++) {
            const float* p = &Wih[(size_t)nrow * 256 + kh * 128 + ks * 32 + quad * 8];
            short8 v;
            for (int j = 0; j < 8; j++) v[j] = (short)f2bf(p[j]);
            wih_frag[tile][ks] = v;
        }
        bias_t[tile] = (kh == 0) ? (bih[nrow] + bhh[nrow]) : 0.0f;
    }

    const int eb = tid >> 5, ek = tid & 31;    // elementwise: local batch, local col
    const int e7 = eb & 7;
    const int hidx = g * 32 + ek;

    for (int i = tid; i < 16 * 512; i += 512) h_lds[i] = 0;
    {   // stage x_lds[0] (swizzled granule = ek ^ e7)
        const unsigned short* src = xT + (size_t)(group * 16 + eb) * 256 + ek * 8;
        *(short8*)&x_lds[0][eb * 256 + (ek ^ e7) * 8] = *(const short8*)src;
    }

    float c = 0.0f;
    float* out_base = out + ((size_t)(group * 16 + eb) * 512 + hidx) * 1024;
    unsigned* my_flags = flags + group * 512;            // 16 flags, 128 B apart
    unsigned* hb_base  = hbuf + group * 8192;            // [2 phase][16 b][256 cp]

    __syncthreads();

    // t=0 x-part
    f32x4 acc0 = f32x4{bias_t[0], bias_t[0], bias_t[0], bias_t[0]};
    f32x4 acc1 = f32x4{bias_t[1], bias_t[1], bias_t[1], bias_t[1]};
    for (int ks = 0; ks < 4; ks++) {
        short8 af = *(const short8*)&x_lds[0][l15 * 256 + (((kh << 4) + (ks << 2) + quad) ^ l7) * 8];
        acc0 = __builtin_amdgcn_mfma_f32_16x16x32_bf16(af, wih_frag[0][ks], acc0, 0, 0, 0);
        acc1 = __builtin_amdgcn_mfma_f32_16x16x32_bf16(af, wih_frag[1][ks], acc1, 0, 0, 0);
    }

    for (int t = 0; t < 1024; t++) {
        // ---- h-part: 8 A-reads feed 16 MFMAs (2 col-tiles) ----
        for (int ks = 0; ks < 8; ks++) {
            short8 af = *(const short8*)&h_lds[l15 * 512 + (((kh << 5) + (ks << 2) + quad) ^ l7) * 8];
            acc0 = __builtin_amdgcn_mfma_f32_16x16x32_bf16(af, whh_frag[0][ks], acc0, 0, 0, 0);
            acc1 = __builtin_amdgcn_mfma_f32_16x16x32_bf16(af, whh_frag[1][ks], acc1, 0, 0, 0);
        }
        {
            const int prow = (kh * 4 + gate) * 16;
            for (int r = 0; r < 4; r++) {
                gates_lds[(prow + quad * 4 + r) * GS + l15]      = acc0[r];
                gates_lds[(prow + quad * 4 + r) * GS + 16 + l15] = acc1[r];
            }
        }

        // prefetch x_{t+1} into the other swizzled buffer
        if (t + 1 < 1024) {
            const unsigned short* src = xT + (size_t)(t + 1) * 8192 +
                                        (size_t)(group * 16 + eb) * 256 + ek * 8;
            *(short8*)&x_lds[(t + 1) & 1][eb * 256 + (ek ^ e7) * 8] = *(const short8*)src;
        }
        __syncthreads();   // gates partials ready; all h_lds reads for step t done

        // ---- elementwise: sum K-half partials, gate math ----
        float iv = gates_lds[(0 * 16 + eb) * GS + ek] + gates_lds[(4 * 16 + eb) * GS + ek];
        float fv = gates_lds[(1 * 16 + eb) * GS + ek] + gates_lds[(5 * 16 + eb) * GS + ek];
        float gv = gates_lds[(2 * 16 + eb) * GS + ek] + gates_lds[(6 * 16 + eb) * GS + ek];
        float ov = gates_lds[(3 * 16 + eb) * GS + ek] + gates_lds[(7 * 16 + eb) * GS + ek];
        iv = fsig(iv); fv = fsig(fv); gv = ftanh(gv); ov = fsig(ov);
        c = fv * c + iv * gv;
        float h = ov * ftanh(c);

        out_stage[tid * OS + (t & 15)] = h;

        // own column straight into h_lds (post-sync, disjoint from other writers)
        unsigned my = f2bf(h);
        {
            int phys = (g * 4 + (ek >> 3)) ^ e7;
            h_lds[eb * 512 + phys * 8 + (ek & 7)] = (unsigned short)my;
        }

        // publish packed bf16x2 dwords (fire now, drain later)
        unsigned nb = (unsigned)__shfl_xor((int)my, 1);
        if (t < 1023 && !(ek & 1)) {
            __hip_atomic_store(&hb_base[(t & 1) * 4096 + eb * 256 + g * 16 + (ek >> 1)],
                               my | (nb << 16), __ATOMIC_RELAXED, __HIP_MEMORY_SCOPE_AGENT);
        }

        if (t == 1023) break;

        // ---- next step's x-part while publish stores drain ----
        acc0 = f32x4{bias_t[0], bias_t[0], bias_t[0], bias_t[0]};
        acc1 = f32x4{bias_t[1], bias_t[1], bias_t[1], bias_t[1]};
        {
            const unsigned short* xb = x_lds[(t + 1) & 1];
            for (int ks = 0; ks < 4; ks++) {
                short8 af = *(const short8*)&xb[l15 * 256 + (((kh << 4) + (ks << 2) + quad) ^ l7) * 8];
                acc0 = __builtin_amdgcn_mfma_f32_16x16x32_bf16(af, wih_frag[0][ks], acc0, 0, 0, 0);
                acc1 = __builtin_amdgcn_mfma_f32_16x16x32_bf16(af, wih_frag[1][ks], acc1, 0, 0, 0);
            }
        }

        // ---- drain own stores, then flag ----
        __builtin_amdgcn_s_waitcnt(0);
        __syncthreads();
        if (tid == 0)
            __hip_atomic_store(&my_flags[g * 32], (unsigned)(t + 1),
                               __ATOMIC_RELAXED, __HIP_MEMORY_SCOPE_AGENT);

        // out flush every 16 steps (own LDS row — no sync needed). MOVED here
        // (after flag): the HBM store burst now drains inside the poll/bulk-load
        // shadow instead of blocking the group-wide flag chain every 16th step.
        if ((t & 15) == 15) {
            int t0 = t & ~15;
            for (int q = 0; q < 4; q++) {
                float4v v = *(const float4v*)&out_stage[tid * OS + q * 4];
                *(float4v*)&out_base[t0 + q * 4] = v;
            }
        }

        // ---- wait for all 16 producers ----
        if (wave == 0 && lane < 16) {
            while (__hip_atomic_load(&my_flags[lane * 32], __ATOMIC_RELAXED,
                                     __HIP_MEMORY_SCOPE_AGENT) <= (unsigned)t) { }
        }
        __syncthreads();

        // ---- bulk-load remote h_t (32 B/thread), write swizzled to h_lds ----
        if ((ek >> 1) != g) {
            const unsigned long long* src =
                (const unsigned long long*)&hb_base[(t & 1) * 4096 + eb * 256 + ek * 8];
            unsigned long long v0 = __hip_atomic_load(src + 0, __ATOMIC_RELAXED, __HIP_MEMORY_SCOPE_AGENT);
            unsigned long long v1 = __hip_atomic_load(src + 1, __ATOMIC_RELAXED, __HIP_MEMORY_SCOPE_AGENT);
            unsigned long long v2 = __hip_atomic_load(src + 2, __ATOMIC_RELAXED, __HIP_MEMORY_SCOPE_AGENT);
            unsigned long long v3 = __hip_atomic_load(src + 3, __ATOMIC_RELAXED, __HIP_MEMORY_SCOPE_AGENT);
            int pa = (2 * ek) ^ e7;
            int pb = (2 * ek + 1) ^ e7;
            *(uint4v*)&h_lds[eb * 512 + pa * 8] =
                uint4v{(unsigned)v0, (unsigned)(v0 >> 32), (unsigned)v1, (unsigned)(v1 >> 32)};
            *(uint4v*)&h_lds[eb * 512 + pb * 8] =
                uint4v{(unsigned)v2, (unsigned)(v2 >> 32), (unsigned)v3, (unsigned)(v3 >> 32)};
        }
        __syncthreads();
    }

    // epilogue: flush last 16 outputs (t = 1008..1023)
    for (int q = 0; q < 4; q++) {
        float4v v = *(const float4v*)&out_stage[tid * OS + q * 4];
        *(float4v*)&out_base[1008 + q * 4] = v;
    }
}

extern "C" void kernel_launch(void* const* d_in, const int* in_sizes, int n_in,
                              void* d_out, int out_size, void* d_ws, size_t ws_size,
                              hipStream_t stream) {
    (void)in_sizes; (void)n_in; (void)out_size; (void)ws_size;
    const float* x   = (const float*)d_in[0];
    const float* Wih = (const float*)d_in[1];
    const float* Whh = (const float*)d_in[2];
    const float* bih = (const float*)d_in[3];
    const float* bhh = (const float*)d_in[4];
    float* out = (float*)d_out;

    char* ws = (char*)d_ws;
    unsigned short* xT = (unsigned short*)ws;                 // 16,777,216 B
    unsigned* flags    = (unsigned*)(ws + 16777216);          // 8 KB
    unsigned* hbuf     = (unsigned*)(ws + 16777216 + 8192);   // 64 KB

    zero_flags<<<8, 256, 0, stream>>>(flags);
    dim3 gT(16, 4, 32);
    x_transpose<<<gT, 256, 0, stream>>>(x, xT);
    lstm_rec<<<32, 512, 0, stream>>>(xT, Wih, Whh, bih, bhh, out, flags, hbuf);
}

// Round 11
// 3010.536 us; speedup vs baseline: 2.3454x; 1.0253x over previous
//
#include <hip/hip_runtime.h>
#include <math.h>

// B=32, D=256, T=1024, H=512, 4H=2048
// Two independent groups of 16 blocks; group owns 16 batches, block owns 32 h-cols.
// Wave layout: wave = (gate, khalf). Each wave: half of K, both 16-col tiles.
// Exchange: publish dword atomics -> s_waitcnt -> flag; poll flags; bulk load.
// LDS: XOR-granule swizzle (16B granule ^ (row&7)), no padding.
// ws: [0,16MB) xT bf16 [T][B][D]; +16MB flags (8KB); then hbuf dw [2grp][2ph][16][256]
//
// ROUND 11 = round-0 champion (best measured: 2980-2986us profiled) + ONE delta:
// PIPELINED 4-DEEP FLAG POLL. The serial load->check->load poll costs up to
// 1.5*RT detection latency after flag visibility; 4 independent atomic loads in
// flight (rotate-check oldest; HW waits only on oldest via counted vmcnt) cut
// expected detection by ~0.5*RT (~500-700 cyc/step).
// Session ledger: r10 flush-move neutral 3007; r2 x-in-regs 3061; r6 per-wave
// consume 3175; r5 single-counter 3468; r1 tagged-data 3852; r7 MFMA-from-hbuf
// 5832; r8/r9 N=8 VGPR-confounded; r3/r4 sc0 medium failed. The agent-scope
// store-visibility chain (~4 LLC RTs/step) is the structural floor; this targets
// the only leg with a software component.

using short8  = __attribute__((ext_vector_type(8))) short;
using f32x4   = __attribute__((ext_vector_type(4))) float;
using float4v = __attribute__((ext_vector_type(4))) float;
using uint4v  = __attribute__((ext_vector_type(4))) unsigned;

__device__ inline unsigned short f2bf(float f) {
    unsigned u = __float_as_uint(f);
    unsigned r = u + 0x7fffu + ((u >> 16) & 1u);
    return (unsigned short)(r >> 16);
}
__device__ inline float fsig(float x) {
    return __builtin_amdgcn_rcpf(1.0f + __expf(-x));
}
__device__ inline float ftanh(float x) {
    return 2.0f * __builtin_amdgcn_rcpf(1.0f + __expf(-2.0f * x)) - 1.0f;
}

__global__ void zero_flags(unsigned* p) {
    p[blockIdx.x * 256 + threadIdx.x] = 0u;
}

// ---------------- Phase 1: xT[t][b][d] = bf16(x[b][d][t]) ----------------
__global__ __launch_bounds__(256) void x_transpose(const float* __restrict__ x,
                                                   unsigned short* __restrict__ xT) {
    __shared__ unsigned short tile[64][65];
    const int tid = threadIdx.x;
    const int t0 = blockIdx.x * 64, d0 = blockIdx.y * 64, b = blockIdx.z;
    for (int p = 0; p < 16; p++) {
        int d = p * 4 + (tid >> 6);
        int t = tid & 63;
        tile[d][t] = f2bf(x[(b * 256 + d0 + d) * 1024 + t0 + t]);
    }
    __syncthreads();
    for (int p = 0; p < 16; p++) {
        int t = p * 4 + (tid >> 6);
        int d = tid & 63;
        xT[(size_t)(t0 + t) * 8192 + b * 256 + d0 + d] = tile[d][t];
    }
}

// ---------------- Phase 2: recurrence ----------------
#define GS 33    // gates_lds row stride (floats)
#define OS 17    // out_stage row stride (floats)

__global__ __launch_bounds__(512) void lstm_rec(const unsigned short* __restrict__ xT,
                                                const float* __restrict__ Wih,
                                                const float* __restrict__ Whh,
                                                const float* __restrict__ bih,
                                                const float* __restrict__ bhh,
                                                float* __restrict__ out,
                                                unsigned* flags,
                                                unsigned* hbuf) {
    __shared__ __align__(16) unsigned short h_lds[16 * 512];      // 16 KB, swizzled
    __shared__ __align__(16) unsigned short x_lds[2][16 * 256];   // 16 KB, swizzled
    __shared__ float gates_lds[8 * 16 * GS];                      // 16.9 KB (2 partials)
    __shared__ float out_stage[512 * OS];                         // 34.8 KB

    const int tid  = threadIdx.x;
    const int wave = tid >> 6;
    const int lane = tid & 63;
    const int quad = lane >> 4, l15 = lane & 15;
    const int l7   = l15 & 7;
    const int group = blockIdx.x & 1;
    const int g     = blockIdx.x >> 1;         // h-slice [32g, 32g+32)
    const int gate  = wave >> 1;               // i,f,g,o
    const int kh    = wave & 1;                // K-half

    // one-time weight preload: 2 col-tiles x (8 h-ks + 4 x-ks), K-range = kh half
    short8 whh_frag[2][8];
    short8 wih_frag[2][4];
    float bias_t[2];
    for (int tile = 0; tile < 2; tile++) {
        const int nrow = gate * 512 + g * 32 + tile * 16 + l15;
        for (int ks = 0; ks < 8; ks++) {
            const float* p = &Whh[(size_t)nrow * 512 + kh * 256 + ks * 32 + quad * 8];
            short8 v;
            for (int j = 0; j < 8; j++) v[j] = (short)f2bf(p[j]);
            whh_frag[tile][ks] = v;
        }
        for (int ks = 0; ks < 4; ks++) {
            const float* p = &Wih[(size_t)nrow * 256 + kh * 128 + ks * 32 + quad * 8];
            short8 v;
            for (int j = 0; j < 8; j++) v[j] = (short)f2bf(p[j]);
            wih_frag[tile][ks] = v;
        }
        bias_t[tile] = (kh == 0) ? (bih[nrow] + bhh[nrow]) : 0.0f;
    }

    const int eb = tid >> 5, ek = tid & 31;    // elementwise: local batch, local col
    const int e7 = eb & 7;
    const int hidx = g * 32 + ek;

    for (int i = tid; i < 16 * 512; i += 512) h_lds[i] = 0;
    {   // stage x_lds[0] (swizzled granule = ek ^ e7)
        const unsigned short* src = xT + (size_t)(group * 16 + eb) * 256 + ek * 8;
        *(short8*)&x_lds[0][eb * 256 + (ek ^ e7) * 8] = *(const short8*)src;
    }

    float c = 0.0f;
    float* out_base = out + ((size_t)(group * 16 + eb) * 512 + hidx) * 1024;
    unsigned* my_flags = flags + group * 512;            // 16 flags, 128 B apart
    unsigned* hb_base  = hbuf + group * 8192;            // [2 phase][16 b][256 cp]

    __syncthreads();

    // t=0 x-part
    f32x4 acc0 = f32x4{bias_t[0], bias_t[0], bias_t[0], bias_t[0]};
    f32x4 acc1 = f32x4{bias_t[1], bias_t[1], bias_t[1], bias_t[1]};
    for (int ks = 0; ks < 4; ks++) {
        short8 af = *(const short8*)&x_lds[0][l15 * 256 + (((kh << 4) + (ks << 2) + quad) ^ l7) * 8];
        acc0 = __builtin_amdgcn_mfma_f32_16x16x32_bf16(af, wih_frag[0][ks], acc0, 0, 0, 0);
        acc1 = __builtin_amdgcn_mfma_f32_16x16x32_bf16(af, wih_frag[1][ks], acc1, 0, 0, 0);
    }

    for (int t = 0; t < 1024; t++) {
        // ---- h-part: 8 A-reads feed 16 MFMAs (2 col-tiles) ----
        for (int ks = 0; ks < 8; ks++) {
            short8 af = *(const short8*)&h_lds[l15 * 512 + (((kh << 5) + (ks << 2) + quad) ^ l7) * 8];
            acc0 = __builtin_amdgcn_mfma_f32_16x16x32_bf16(af, whh_frag[0][ks], acc0, 0, 0, 0);
            acc1 = __builtin_amdgcn_mfma_f32_16x16x32_bf16(af, whh_frag[1][ks], acc1, 0, 0, 0);
        }
        {
            const int prow = (kh * 4 + gate) * 16;
            for (int r = 0; r < 4; r++) {
                gates_lds[(prow + quad * 4 + r) * GS + l15]      = acc0[r];
                gates_lds[(prow + quad * 4 + r) * GS + 16 + l15] = acc1[r];
            }
        }

        // prefetch x_{t+1} into the other swizzled buffer
        if (t + 1 < 1024) {
            const unsigned short* src = xT + (size_t)(t + 1) * 8192 +
                                        (size_t)(group * 16 + eb) * 256 + ek * 8;
            *(short8*)&x_lds[(t + 1) & 1][eb * 256 + (ek ^ e7) * 8] = *(const short8*)src;
        }
        __syncthreads();   // gates partials ready; all h_lds reads for step t done

        // ---- elementwise: sum K-half partials, gate math ----
        float iv = gates_lds[(0 * 16 + eb) * GS + ek] + gates_lds[(4 * 16 + eb) * GS + ek];
        float fv = gates_lds[(1 * 16 + eb) * GS + ek] + gates_lds[(5 * 16 + eb) * GS + ek];
        float gv = gates_lds[(2 * 16 + eb) * GS + ek] + gates_lds[(6 * 16 + eb) * GS + ek];
        float ov = gates_lds[(3 * 16 + eb) * GS + ek] + gates_lds[(7 * 16 + eb) * GS + ek];
        iv = fsig(iv); fv = fsig(fv); gv = ftanh(gv); ov = fsig(ov);
        c = fv * c + iv * gv;
        float h = ov * ftanh(c);

        out_stage[tid * OS + (t & 15)] = h;

        // own column straight into h_lds (post-sync, disjoint from other writers)
        unsigned my = f2bf(h);
        {
            int phys = (g * 4 + (ek >> 3)) ^ e7;
            h_lds[eb * 512 + phys * 8 + (ek & 7)] = (unsigned short)my;
        }

        // publish packed bf16x2 dwords (fire now, drain later)
        unsigned nb = (unsigned)__shfl_xor((int)my, 1);
        if (t < 1023 && !(ek & 1)) {
            __hip_atomic_store(&hb_base[(t & 1) * 4096 + eb * 256 + g * 16 + (ek >> 1)],
                               my | (nb << 16), __ATOMIC_RELAXED, __HIP_MEMORY_SCOPE_AGENT);
        }

        // out flush every 16 steps (own LDS row — no sync needed)
        if ((t & 15) == 15) {
            int t0 = t & ~15;
            for (int q = 0; q < 4; q++) {
                float4v v = *(const float4v*)&out_stage[tid * OS + q * 4];
                *(float4v*)&out_base[t0 + q * 4] = v;
            }
        }

        if (t == 1023) break;

        // ---- next step's x-part while publish stores drain ----
        acc0 = f32x4{bias_t[0], bias_t[0], bias_t[0], bias_t[0]};
        acc1 = f32x4{bias_t[1], bias_t[1], bias_t[1], bias_t[1]};
        {
            const unsigned short* xb = x_lds[(t + 1) & 1];
            for (int ks = 0; ks < 4; ks++) {
                short8 af = *(const short8*)&xb[l15 * 256 + (((kh << 4) + (ks << 2) + quad) ^ l7) * 8];
                acc0 = __builtin_amdgcn_mfma_f32_16x16x32_bf16(af, wih_frag[0][ks], acc0, 0, 0, 0);
                acc1 = __builtin_amdgcn_mfma_f32_16x16x32_bf16(af, wih_frag[1][ks], acc1, 0, 0, 0);
            }
        }

        // ---- drain own stores, then flag ----
        __builtin_amdgcn_s_waitcnt(0);
        __syncthreads();
        if (tid == 0)
            __hip_atomic_store(&my_flags[g * 32], (unsigned)(t + 1),
                               __ATOMIC_RELAXED, __HIP_MEMORY_SCOPE_AGENT);

        // ---- wait for all 16 producers: PIPELINED 4-DEEP POLL. 4 independent
        // atomic loads in flight; check rotates through them oldest-first, so HW
        // waits only on the oldest (counted vmcnt) while 3 stay in flight.
        // Detection lag after flag visibility ~RT/4-burst instead of serial RT. ----
        if (wave == 0 && lane < 16) {
            const unsigned* fp = &my_flags[lane * 32];
            unsigned v0 = __hip_atomic_load(fp, __ATOMIC_RELAXED, __HIP_MEMORY_SCOPE_AGENT);
            unsigned v1 = __hip_atomic_load(fp, __ATOMIC_RELAXED, __HIP_MEMORY_SCOPE_AGENT);
            unsigned v2 = __hip_atomic_load(fp, __ATOMIC_RELAXED, __HIP_MEMORY_SCOPE_AGENT);
            unsigned v3 = __hip_atomic_load(fp, __ATOMIC_RELAXED, __HIP_MEMORY_SCOPE_AGENT);
            while (v0 <= (unsigned)t) {
                v0 = v1; v1 = v2; v2 = v3;
                v3 = __hip_atomic_load(fp, __ATOMIC_RELAXED, __HIP_MEMORY_SCOPE_AGENT);
            }
        }
        __syncthreads();

        // ---- bulk-load remote h_t (32 B/thread), write swizzled to h_lds ----
        if ((ek >> 1) != g) {
            const unsigned long long* src =
                (const unsigned long long*)&hb_base[(t & 1) * 4096 + eb * 256 + ek * 8];
            unsigned long long v0 = __hip_atomic_load(src + 0, __ATOMIC_RELAXED, __HIP_MEMORY_SCOPE_AGENT);
            unsigned long long v1 = __hip_atomic_load(src + 1, __ATOMIC_RELAXED, __HIP_MEMORY_SCOPE_AGENT);
            unsigned long long v2 = __hip_atomic_load(src + 2, __ATOMIC_RELAXED, __HIP_MEMORY_SCOPE_AGENT);
            unsigned long long v3 = __hip_atomic_load(src + 3, __ATOMIC_RELAXED, __HIP_MEMORY_SCOPE_AGENT);
            int pa = (2 * ek) ^ e7;
            int pb = (2 * ek + 1) ^ e7;
            *(uint4v*)&h_lds[eb * 512 + pa * 8] =
                uint4v{(unsigned)v0, (unsigned)(v0 >> 32), (unsigned)v1, (unsigned)(v1 >> 32)};
            *(uint4v*)&h_lds[eb * 512 + pb * 8] =
                uint4v{(unsigned)v2, (unsigned)(v2 >> 32), (unsigned)v3, (unsigned)(v3 >> 32)};
        }
        __syncthreads();
    }

    // epilogue: flush last 16 outputs (t = 1008..1023)
    for (int q = 0; q < 4; q++) {
        float4v v = *(const float4v*)&out_stage[tid * OS + q * 4];
        *(float4v*)&out_base[1008 + q * 4] = v;
    }
}

extern "C" void kernel_launch(void* const* d_in, const int* in_sizes, int n_in,
                              void* d_out, int out_size, void* d_ws, size_t ws_size,
                              hipStream_t stream) {
    (void)in_sizes; (void)n_in; (void)out_size; (void)ws_size;
    const float* x   = (const float*)d_in[0];
    const float* Wih = (const float*)d_in[1];
    const float* Whh = (const float*)d_in[2];
    const float* bih = (const float*)d_in[3];
    const float* bhh = (const float*)d_in[4];
    float* out = (float*)d_out;

    char* ws = (char*)d_ws;
    unsigned short* xT = (unsigned short*)ws;                 // 16,777,216 B
    unsigned* flags    = (unsigned*)(ws + 16777216);          // 8 KB
    unsigned* hbuf     = (unsigned*)(ws + 16777216 + 8192);   // 64 KB

    zero_flags<<<8, 256, 0, stream>>>(flags);
    dim3 gT(16, 4, 32);
    x_transpose<<<gT, 256, 0, stream>>>(x, xT);
    lstm_rec<<<32, 512, 0, stream>>>(xT, Wih, Whh, bih, bhh, out, flags, hbuf);
}